// Round 3
// baseline (61.043 us; speedup 1.0000x reference)
//
#include <hip/hip_runtime.h>

// Depth-4 path signature, C=10, L=64, B=2048.
// R2: fully lane-local formulation — NO barriers, NO cross-lane traffic in the
// main loop. Each lane owns one (i,j) pair: scalars s1=S1[i], s2=S2[ij],
// pairs s3[5]=S3[ij,:], s4[50]=S4[ij,:,:]. Chen/Horner step (verified R0/R1):
//   u1=s1+di/4; v1=s1+di/3; w1=s1+di/2
//   u2=s2+u1*dj/3; v2=s2+v1*dj/2; s2+=w1*dj; s1+=di
//   u3[k]=s3[k]+u2*dk/2; s3[k]+=v2*dk; s4[k][l]+=u3[k]*dl
// dx row is a wave-uniform LDS broadcast; di/dj are 10-bank scattered reads.
// Block = 256 thr = 2 batch elems x 128 lanes (lanes 100..127 exec-masked).

typedef float f2 __attribute__((ext_vector_type(2)));
typedef float f4 __attribute__((ext_vector_type(4)));

constexpr int C = 10;
constexpr int L = 64;
constexpr int NSTEP = L - 1;                   // 63
constexpr int OUTSZ = 10 + 100 + 1000 + 10000; // 11110
constexpr int ROWP = 12;                       // padded dx row stride (floats)

// d = {a.lo*b.lo+c.lo, a.lo*b.hi+c.hi}  (broadcast a.lo)
__device__ __forceinline__ f2 pk_fma_blo(f2 a, f2 b, f2 c) {
  f2 d;
  asm("v_pk_fma_f32 %0, %1, %2, %3 op_sel:[0,0,0] op_sel_hi:[0,1,1]"
      : "=v"(d) : "v"(a), "v"(b), "v"(c));
  return d;
}
// d = {a.hi*b.lo+c.lo, a.hi*b.hi+c.hi}  (broadcast a.hi)
__device__ __forceinline__ f2 pk_fma_bhi(f2 a, f2 b, f2 c) {
  f2 d;
  asm("v_pk_fma_f32 %0, %1, %2, %3 op_sel:[1,0,0] op_sel_hi:[1,1,1]"
      : "=v"(d) : "v"(a), "v"(b), "v"(c));
  return d;
}
__device__ __forceinline__ void pk_fma_acc_blo(f2& acc, f2 a, f2 b) {
  asm("v_pk_fma_f32 %0, %1, %2, %0 op_sel:[0,0,0] op_sel_hi:[0,1,1]"
      : "+v"(acc) : "v"(a), "v"(b));
}
__device__ __forceinline__ void pk_fma_acc_bhi(f2& acc, f2 a, f2 b) {
  asm("v_pk_fma_f32 %0, %1, %2, %0 op_sel:[1,0,0] op_sel_hi:[1,1,1]"
      : "+v"(acc) : "v"(a), "v"(b));
}

__global__ __launch_bounds__(256) void sig4_kernel(
    const float* __restrict__ x, float* __restrict__ out)
{
  const int t = threadIdx.x;
  const int half = t >> 7;     // batch elem within block
  const int tt = t & 127;      // lane within elem

  __shared__ float dxs[2 * NSTEP * ROWP];  // [2][63][12]
  __shared__ float pl[2 * C * L];          // staged path (prologue only)

  // coalesced path load: 1280 floats
  const float* __restrict__ xb = x + (size_t)blockIdx.x * (2 * C * L);
  for (int i = t; i < 2 * C * L; i += 256) pl[i] = xb[i];
  __syncthreads();
  // increments dx[e][s][c] = path[e][c][s+1] - path[e][c][s]
  for (int i = t; i < 2 * NSTEP * C; i += 256) {
    int e = i / (NSTEP * C), r = i - e * (NSTEP * C);
    int s = r / C, c = r - s * C;
    dxs[e * (NSTEP * ROWP) + s * ROWP + c] =
        pl[e * (C * L) + c * L + s + 1] - pl[e * (C * L) + c * L + s];
  }
  __syncthreads();

  const int p = (tt < 100) ? tt : 0;       // clamp idle lanes (LDS safety)
  const int ii = p / 10;
  const int jj = p - ii * 10;

  float s1 = 0.f, s2 = 0.f;
  f2 s3[5];
  f2 s4[50];                               // flat kl pairs: pair m -> (k=2m/10... m covers kl=2m,2m+1)
  #pragma unroll
  for (int k = 0; k < 5; ++k) s3[k] = f2{0.f, 0.f};
  #pragma unroll
  for (int m = 0; m < 50; ++m) s4[m] = f2{0.f, 0.f};

  const float* row = dxs + half * (NSTEP * ROWP);

  for (int s = 0; s < NSTEP; ++s, row += ROWP) {
    const f2* rp = (const f2*)row;         // wave-uniform broadcast reads
    f2 dp0 = rp[0], dp1 = rp[1], dp2 = rp[2], dp3 = rp[3], dp4 = rp[4];
    float di = row[ii];                    // scattered, 10 banks, conflict-free
    float dj = row[jj];
    float u1 = fmaf(di, 0.25f, s1);
    float v1 = fmaf(di, (1.f / 3.f), s1);
    float w1 = fmaf(di, 0.5f, s1);
    float u2 = fmaf(u1, dj * (1.f / 3.f), s2);
    float v2 = fmaf(v1, dj * 0.5f, s2);
    s2 = fmaf(w1, dj, s2);
    s1 += di;
    f2 uv = {u2 * 0.5f, v2};               // lo=u2/2, hi=v2
    f2 u3[5];
    u3[0] = pk_fma_blo(uv, dp0, s3[0]); s3[0] = pk_fma_bhi(uv, dp0, s3[0]);
    u3[1] = pk_fma_blo(uv, dp1, s3[1]); s3[1] = pk_fma_bhi(uv, dp1, s3[1]);
    u3[2] = pk_fma_blo(uv, dp2, s3[2]); s3[2] = pk_fma_bhi(uv, dp2, s3[2]);
    u3[3] = pk_fma_blo(uv, dp3, s3[3]); s3[3] = pk_fma_bhi(uv, dp3, s3[3]);
    u3[4] = pk_fma_blo(uv, dp4, s3[4]); s3[4] = pk_fma_bhi(uv, dp4, s3[4]);
    // s4[k][l] += u3[k]*dx[l]; rows k=2kp (lo of u3[kp]) and k=2kp+1 (hi)
    #pragma unroll
    for (int kp = 0; kp < 5; ++kp) {
      pk_fma_acc_blo(s4[(2 * kp) * 5 + 0], u3[kp], dp0);
      pk_fma_acc_blo(s4[(2 * kp) * 5 + 1], u3[kp], dp1);
      pk_fma_acc_blo(s4[(2 * kp) * 5 + 2], u3[kp], dp2);
      pk_fma_acc_blo(s4[(2 * kp) * 5 + 3], u3[kp], dp3);
      pk_fma_acc_blo(s4[(2 * kp) * 5 + 4], u3[kp], dp4);
      pk_fma_acc_bhi(s4[(2 * kp + 1) * 5 + 0], u3[kp], dp0);
      pk_fma_acc_bhi(s4[(2 * kp + 1) * 5 + 1], u3[kp], dp1);
      pk_fma_acc_bhi(s4[(2 * kp + 1) * 5 + 2], u3[kp], dp2);
      pk_fma_acc_bhi(s4[(2 * kp + 1) * 5 + 3], u3[kp], dp3);
      pk_fma_acc_bhi(s4[(2 * kp + 1) * 5 + 4], u3[kp], dp4);
    }
  }

  // ---- epilogue: each lane stores its own slices (8B-aligned f2 stores) ----
  if (tt < 100) {
    const size_t b = (size_t)blockIdx.x * 2 + half;
    float* __restrict__ ob = out + b * OUTSZ;
    if (jj == 0) ob[ii] = s1;              // level 1
    ob[10 + tt] = s2;                      // level 2
    #pragma unroll
    for (int kp = 0; kp < 5; ++kp)         // level 3: 110 + tt*10 + k
      *(f2*)(ob + 110 + tt * 10 + 2 * kp) = s3[kp];
    #pragma unroll
    for (int m = 0; m < 50; ++m)           // level 4: 1110 + tt*100 + kl
      *(f2*)(ob + 1110 + tt * 100 + 2 * m) = s4[m];
  }
}

extern "C" void kernel_launch(void* const* d_in, const int* in_sizes, int n_in,
                              void* d_out, int out_size, void* d_ws, size_t ws_size,
                              hipStream_t stream) {
  const float* x = (const float*)d_in[0];
  float* out = (float*)d_out;
  const int batch = in_sizes[0] / (C * L);   // 2048
  sig4_kernel<<<dim3(batch / 2), dim3(256), 0, stream>>>(x, out);
}